// Round 5
// baseline (270.036 us; speedup 1.0000x reference)
//
#include <hip/hip_runtime.h>

// GIoU loss, 3D boxes, matched pairs, sum-reduced and negated.
// Box row: [x1, y1, x2, y2, z1, z2] (6 f32).
//
// R4 ablation: perfectly-coalesced pure-read probe pinned at the SAME
// 73.5 us / 2.6 TB/s as every GIoU structure (R1 strided, R2 LDS-staged).
// Limiter is regime, not structure. FETCH_SIZE == half the footprint every
// time -> half the lines are served by L3 (harness input-restore leaves them
// there), half by HBM, ~1.3 TB/s each. R5 isolates this with NONTEMPORAL
// loads (global_load_dwordx4 nt): bypass cache allocation, stream from HBM.
//   dispatch 1: probe_nt_kernel — R4 probe structure + nt loads (A/B vs 73.5)
//   dispatch 2: giou_nt_kernel  — production GIoU, quad-batched, nt loads
//   dispatch 3: giou_final_kernel

namespace {

constexpr float kEps     = 1e-7f;
constexpr int   kThreads = 256;     // 4 waves
constexpr int   kBlocks  = 2048;    // 8 blocks/CU nominal, grid-stride

using v4f = __attribute__((ext_vector_type(4))) float;

__device__ __forceinline__ v4f ntload(const v4f* p) {
    return __builtin_nontemporal_load(p);
}

__device__ __forceinline__ float giou1(
    float px1, float py1, float px2, float py2, float pz1, float pz2,
    float tx1, float ty1, float tx2, float ty2, float tz1, float tz2)
{
    float vol1 = (px2 - px1) * (py2 - py1) * (pz2 - pz1);
    float vol2 = (tx2 - tx1) * (ty2 - ty1) * (tz2 - tz1);

    float ix = fmaxf(fminf(px2, tx2) - fmaxf(px1, tx1), 0.0f);
    float iy = fmaxf(fminf(py2, ty2) - fmaxf(py1, ty1), 0.0f);
    float iz = fmaxf(fminf(pz2, tz2) - fmaxf(pz1, tz1), 0.0f);
    float inter = ix * iy * iz;
    float uni = vol1 + vol2 - inter;
    float iou = inter / uni;

    float ex = fmaxf(fmaxf(px2, tx2) - fminf(px1, tx1), 0.0f);
    float ey = fmaxf(fmaxf(py2, ty2) - fminf(py1, ty1), 0.0f);
    float ez = fmaxf(fmaxf(pz2, tz2) - fminf(pz1, tz1), 0.0f);
    float enc = ex * ey * ez + kEps;

    return iou - (enc - uni) / enc;
}

__device__ __forceinline__ double block_reduce(double acc, int tid) {
    #pragma unroll
    for (int off = 32; off > 0; off >>= 1)
        acc += __shfl_down(acc, off, 64);
    __shared__ double smem[kThreads / 64];
    const int lane = tid & 63;
    const int wid  = tid >> 6;
    if (lane == 0) smem[wid] = acc;
    __syncthreads();
    double s = 0.0;
    if (tid == 0) {
        #pragma unroll
        for (int w = 0; w < kThreads / 64; ++w) s += smem[w];
    }
    return s;
}

// ---- Dispatch 1: nt-load yardstick, structure identical to R4's probe.
__global__ __launch_bounds__(kThreads) void probe_nt_kernel(
    const v4f* __restrict__ p4, const v4f* __restrict__ t4,
    double* __restrict__ partials, int n4)
{
    float acc = 0.0f;
    const int stride = gridDim.x * blockDim.x;
    for (int i = blockIdx.x * blockDim.x + threadIdx.x; i < n4; i += stride) {
        v4f a = ntload(p4 + i);
        v4f b = ntload(t4 + i);
        acc += ((a[0] + a[1]) + (a[2] + a[3])) + ((b[0] + b[1]) + (b[2] + b[3]));
    }
    double s = block_reduce((double)acc, threadIdx.x);
    if (threadIdx.x == 0) partials[blockIdx.x] = s;  // dead: overwritten by dispatch 2
}

// ---- Dispatch 2: production GIoU. Quad-batched (4 boxes = 6 v4f per array),
// all 12 nt loads issued before any math.
__global__ __launch_bounds__(kThreads) void giou_nt_kernel(
    const float* __restrict__ pred, const float* __restrict__ targ,
    double* __restrict__ partials, int nquads)
{
    const v4f* __restrict__ p4 = reinterpret_cast<const v4f*>(pred);
    const v4f* __restrict__ t4 = reinterpret_cast<const v4f*>(targ);

    double acc = 0.0;
    const int stride = gridDim.x * blockDim.x;
    for (int q = blockIdx.x * blockDim.x + threadIdx.x; q < nquads; q += stride) {
        const size_t b = (size_t)q * 6;
        v4f P0 = ntload(p4 + b + 0), P1 = ntload(p4 + b + 1), P2 = ntload(p4 + b + 2);
        v4f P3 = ntload(p4 + b + 3), P4 = ntload(p4 + b + 4), P5 = ntload(p4 + b + 5);
        v4f T0 = ntload(t4 + b + 0), T1 = ntload(t4 + b + 1), T2 = ntload(t4 + b + 2);
        v4f T3 = ntload(t4 + b + 3), T4 = ntload(t4 + b + 4), T5 = ntload(t4 + b + 5);

        // quad layout: box0=(f0.xyzw, f1.xy)  box1=(f1.zw, f2.xyzw)
        //              box2=(f3.xyzw, f4.xy)  box3=(f4.zw, f5.xyzw)
        float g0 = giou1(P0[0], P0[1], P0[2], P0[3], P1[0], P1[1],
                         T0[0], T0[1], T0[2], T0[3], T1[0], T1[1]);
        float g1 = giou1(P1[2], P1[3], P2[0], P2[1], P2[2], P2[3],
                         T1[2], T1[3], T2[0], T2[1], T2[2], T2[3]);
        float g2 = giou1(P3[0], P3[1], P3[2], P3[3], P4[0], P4[1],
                         T3[0], T3[1], T3[2], T3[3], T4[0], T4[1]);
        float g3 = giou1(P4[2], P4[3], P5[0], P5[1], P5[2], P5[3],
                         T4[2], T4[3], T5[0], T5[1], T5[2], T5[3]);
        acc += ((double)g0 + (double)g1) + ((double)g2 + (double)g3);
    }

    double s = block_reduce(acc, threadIdx.x);
    if (threadIdx.x == 0) partials[blockIdx.x] = s;
}

// ---- Dispatch 3: final reduction (+ defensive tail for nboxes % 4).
__global__ __launch_bounds__(kThreads) void giou_final_kernel(
    const double* __restrict__ partials, int n,
    const float* __restrict__ pred, const float* __restrict__ targ,
    int tail_start, int nboxes, float* __restrict__ out)
{
    double acc = 0.0;
    for (int i = threadIdx.x; i < n; i += kThreads) acc += partials[i];
    double s = block_reduce(acc, threadIdx.x);
    if (threadIdx.x == 0) {
        for (int bx = tail_start; bx < nboxes; ++bx) {   // dead for N=4e6
            const float* pp = pred + (size_t)bx * 6;
            const float* tt = targ + (size_t)bx * 6;
            s += (double)giou1(pp[0], pp[1], pp[2], pp[3], pp[4], pp[5],
                               tt[0], tt[1], tt[2], tt[3], tt[4], tt[5]);
        }
        out[0] = (float)(-1.0 * s);   // LOSS_WEIGHT * -1 * sum
    }
}

}  // namespace

extern "C" void kernel_launch(void* const* d_in, const int* in_sizes, int n_in,
                              void* d_out, int out_size, void* d_ws, size_t ws_size,
                              hipStream_t stream) {
    const float* pred = (const float*)d_in[0];
    const float* targ = (const float*)d_in[1];
    float* out = (float*)d_out;

    const int nboxes = in_sizes[0] / 6;       // 4,000,000
    const int nquads = nboxes / 4;            // 1,000,000
    const int n4     = in_sizes[0] / 4;       // 6,000,000 v4f per array

    double* partials = (double*)d_ws;         // kBlocks * 8 B = 16 KiB

    probe_nt_kernel<<<kBlocks, kThreads, 0, stream>>>(
        (const v4f*)pred, (const v4f*)targ, partials, n4);
    giou_nt_kernel<<<kBlocks, kThreads, 0, stream>>>(
        pred, targ, partials, nquads);
    giou_final_kernel<<<1, kThreads, 0, stream>>>(
        partials, kBlocks, pred, targ, nquads * 4, nboxes, out);
}

// Round 6
// 203.627 us; speedup vs baseline: 1.3261x; 1.3261x over previous
//
#include <hip/hip_runtime.h>

// GIoU loss, 3D boxes, matched pairs, sum-reduced and negated.
// Box row: [x1, y1, x2, y2, z1, z2] (6 f32). Pair of boxes = 48 B = 3 float4.
//
// R1-R5 ablation history: four structures (strided direct, global_load_lds+
// barriers, pure-read coalesced probe, quad-ILP direct) and nontemporal loads
// all pin at 71-80 us for the 192 MB footprint (~2.6-2.7 TB/s delivered).
// The pure-read probe itself sits at the same number -> this is the chip's
// cold-read service ceiling for this regime (the 6.3 TB/s figure is
// read+write copy traffic), not a kernel-structure artifact. nt loads lose
// the harness-restore L3 hits and regress (80 us, FETCH 96->136 MB).
//
// Production build: single compute dispatch (pair/thread, 3x float4 per
// array, grid-stride) + per-block fp32 atomicAdd into d_out (absmax
// threshold 6.4e4 -> atomic ordering noise irrelevant). d_out is re-poisoned
// 0xAA before every timed replay, so a 4-byte hipMemsetAsync is enqueued
// each call (memset nodes are graph-capturable).

namespace {

constexpr float kEps     = 1e-7f;
constexpr int   kThreads = 256;     // 4 waves
constexpr int   kBlocks  = 2048;    // 8 blocks/CU nominal, grid-stride

__device__ __forceinline__ float giou1(
    float px1, float py1, float px2, float py2, float pz1, float pz2,
    float tx1, float ty1, float tx2, float ty2, float tz1, float tz2)
{
    float vol1 = (px2 - px1) * (py2 - py1) * (pz2 - pz1);
    float vol2 = (tx2 - tx1) * (ty2 - ty1) * (tz2 - tz1);

    float ix = fmaxf(fminf(px2, tx2) - fmaxf(px1, tx1), 0.0f);
    float iy = fmaxf(fminf(py2, ty2) - fmaxf(py1, ty1), 0.0f);
    float iz = fmaxf(fminf(pz2, tz2) - fmaxf(pz1, tz1), 0.0f);
    float inter = ix * iy * iz;
    float uni = vol1 + vol2 - inter;
    float iou = inter / uni;

    float ex = fmaxf(fmaxf(px2, tx2) - fminf(px1, tx1), 0.0f);
    float ey = fmaxf(fmaxf(py2, ty2) - fminf(py1, ty1), 0.0f);
    float ez = fmaxf(fmaxf(pz2, tz2) - fminf(pz1, tz1), 0.0f);
    float enc = ex * ey * ez + kEps;

    return iou - (enc - uni) / enc;
}

__global__ __launch_bounds__(kThreads) void giou_loss_kernel(
    const float* __restrict__ pred, const float* __restrict__ targ,
    float* __restrict__ out, int npairs, int nboxes)
{
    const float4* __restrict__ p4 = reinterpret_cast<const float4*>(pred);
    const float4* __restrict__ t4 = reinterpret_cast<const float4*>(targ);

    double acc = 0.0;
    const int stride = gridDim.x * blockDim.x;
    for (int i = blockIdx.x * blockDim.x + threadIdx.x; i < npairs; i += stride) {
        const size_t b = 3 * (size_t)i;
        float4 pa = p4[b + 0];
        float4 pb = p4[b + 1];
        float4 pc = p4[b + 2];
        float4 ta = t4[b + 0];
        float4 tb = t4[b + 1];
        float4 tc = t4[b + 2];

        // box 2i  : x1=a.x y1=a.y x2=a.z y2=a.w z1=b.x z2=b.y
        // box 2i+1: x1=b.z y1=b.w x2=c.x y2=c.y z1=c.z z2=c.w
        float g0 = giou1(pa.x, pa.y, pa.z, pa.w, pb.x, pb.y,
                         ta.x, ta.y, ta.z, ta.w, tb.x, tb.y);
        float g1 = giou1(pb.z, pb.w, pc.x, pc.y, pc.z, pc.w,
                         tb.z, tb.w, tc.x, tc.y, tc.z, tc.w);
        acc += (double)g0 + (double)g1;
    }

    // Defensive odd-box tail (dead for N = 4e6).
    if ((nboxes & 1) && blockIdx.x == 0 && threadIdx.x == 0) {
        const float* pp = pred + (size_t)(nboxes - 1) * 6;
        const float* tt = targ + (size_t)(nboxes - 1) * 6;
        acc += (double)giou1(pp[0], pp[1], pp[2], pp[3], pp[4], pp[5],
                             tt[0], tt[1], tt[2], tt[3], tt[4], tt[5]);
    }

    // Wave (64-lane) butterfly, then cross-wave via LDS.
    #pragma unroll
    for (int off = 32; off > 0; off >>= 1)
        acc += __shfl_down(acc, off, 64);

    __shared__ double smem[kThreads / 64];
    const int lane = threadIdx.x & 63;
    const int wid  = threadIdx.x >> 6;
    if (lane == 0) smem[wid] = acc;
    __syncthreads();
    if (threadIdx.x == 0) {
        double s = 0.0;
        #pragma unroll
        for (int w = 0; w < kThreads / 64; ++w) s += smem[w];
        // LOSS_WEIGHT * -1 * sum; device-scope atomic (G12), one per block.
        atomicAdd(out, (float)(-s));
    }
}

}  // namespace

extern "C" void kernel_launch(void* const* d_in, const int* in_sizes, int n_in,
                              void* d_out, int out_size, void* d_ws, size_t ws_size,
                              hipStream_t stream) {
    const float* pred = (const float*)d_in[0];
    const float* targ = (const float*)d_in[1];
    float* out = (float*)d_out;

    const int nboxes = in_sizes[0] / 6;    // 4,000,000
    const int npairs = nboxes / 2;         // 2,000,000

    // d_out is re-poisoned to 0xAA before every timed replay: zero it on
    // stream each call (memset nodes are supported in graph capture).
    (void)hipMemsetAsync(out, 0, sizeof(float), stream);

    giou_loss_kernel<<<kBlocks, kThreads, 0, stream>>>(
        pred, targ, out, npairs, nboxes);
}